// Round 4
// baseline (319.895 us; speedup 1.0000x reference)
//
#include <hip/hip_runtime.h>
#include <math.h>

// ---------------------------------------------------------------------------
// SiameseRPN one-branch, restructured:
//  K0: pad target_feat -> tfp[512][34][34]; transpose w_target -> wT[ci][co][9];
//      zero padded t' buffer tP[256][38][40]; Bfold[128] tail
//  K1: blocks 0..255  : 3x3 conv target + BN (+0.1 factor folded) -> tP interior
//                       (VALU-bound, launches first, hidden under the fold)
//      blocks 256..831: fold w_merge_cls into w_template -> WfoldT[4608][128]
//                       576 blocks, float4 8-row batches -> HBM-BW-bound
//  K2: Z2 partials: Z2P[n][kc=32][uv=49][eh=128], K-split over ci (16 ci/chunk)
//  K3: merged[n][64][32][32] = sum_{h128,u,v} t'[128n+eh] * Z2[n][eh][uv]
//  K4: 1x1 heads (cls 18, box 36) + paired softmax -> d_out
// Workspace: 3,283,072 floats = 13.2 MB (unchanged from round 2)
// ---------------------------------------------------------------------------

#define WS_TFP 0            // 512*34*34      = 591872
#define WS_WT  591872       // 512*256*9      = 1179648
#define WS_TP  1771520      // 256*38*40      = 389120
#define WS_WF  2160640      // 4608*128       = 589824
#define WS_BF  2750464      // 128
#define WS_Z2P 2750592      // 2*32*49*128    = 401408
#define WS_MRG 3152000      // 2*64*32*32     = 131072
// total 3283072 floats

__global__ __launch_bounds__(256) void k0_prep(
    const float* __restrict__ tfeat,   // target_feat 512*32*32
    const float* __restrict__ wtgt,    // w_target 256*512*9
    const float* __restrict__ wm,      // w_merge_cls 256
    const float* __restrict__ btpl,    // b_template 16384
    float* ws)
{
  const int N0 = 591872, N1 = 1179648, N2 = 389120;
  const int total = N0 + N1 + N2;
  for (int idx = blockIdx.x * 256 + threadIdx.x; idx < total + 128; idx += gridDim.x * 256) {
    if (idx < N0) {
      int ci = idx / 1156, r = idx % 1156;
      int yy = r / 34, xx = r % 34;
      float v = 0.f;
      if (yy >= 1 && yy <= 32 && xx >= 1 && xx <= 32)
        v = tfeat[ci * 1024 + (yy - 1) * 32 + (xx - 1)];
      ws[WS_TFP + idx] = v;
    } else if (idx < N0 + N1) {
      int j = idx - N0;
      int ci = j / 2304, r = j % 2304;
      int co = r / 9, pq = r % 9;
      ws[WS_WT + j] = wtgt[co * 4608 + ci * 9 + pq];
    } else if (idx < total) {
      ws[WS_TP + (idx - N0 - N1)] = 0.f;
    } else {
      // Bfold[eh] = sum_cl wm[h*128+cl] * b_template[e*256+h*128+cl]
      const int eh = idx - total;
      const int e = eh >> 1, h = eh & 1;
      const float* wmp = wm + h * 128;
      const float* bp = btpl + e * 256 + h * 128;
      float s = 0.f;
      for (int cl = 0; cl < 128; cl++) s = fmaf(wmp[cl], bp[cl], s);
      ws[WS_BF + eh] = s;
    }
  }
}

__global__ __launch_bounds__(256) void k1_fold_conv(
    const float* __restrict__ wtpl,    // w_template 16384*4608
    const float* __restrict__ wm,      // w_merge_cls 256
    const float* __restrict__ btgt,    // b_target 256
    const float* __restrict__ gamma, const float* __restrict__ beta,
    const float* __restrict__ mean, const float* __restrict__ var,
    float* ws)
{
  __shared__ float wm_l[256];
  const int tid = threadIdx.x;
  const int bid = blockIdx.x;

  if (bid >= 256) {
    // ---------------- FOLD path (HBM-BW-bound) ----------------
    // 576 blocks: e in [0,64), chunk in [0,9). tid>=128 -> h=1 half.
    const int fb = bid - 256;
    const int chunk = fb % 9;
    const int e = fb / 9;
    const int h = tid >> 7;
    const int lt = tid & 127;
    const int eh = 2 * e + h;
    wm_l[tid] = wm[tid];
    __syncthreads();
    const float* base = wtpl + (size_t)(e * 256 + h * 128) * 4608 + chunk * 512 + lt * 4;
    const float* wmh = wm_l + h * 128;
    float4 acc = make_float4(0.f, 0.f, 0.f, 0.f);
    #pragma unroll 2
    for (int r = 0; r < 128; r += 8) {
      // 8 independent float4 loads in flight (1 KB/wave each)
      const float4 v0 = *(const float4*)(base + (size_t)(r + 0) * 4608);
      const float4 v1 = *(const float4*)(base + (size_t)(r + 1) * 4608);
      const float4 v2 = *(const float4*)(base + (size_t)(r + 2) * 4608);
      const float4 v3 = *(const float4*)(base + (size_t)(r + 3) * 4608);
      const float4 v4 = *(const float4*)(base + (size_t)(r + 4) * 4608);
      const float4 v5 = *(const float4*)(base + (size_t)(r + 5) * 4608);
      const float4 v6 = *(const float4*)(base + (size_t)(r + 6) * 4608);
      const float4 v7 = *(const float4*)(base + (size_t)(r + 7) * 4608);
      const float w0 = wmh[r + 0], w1 = wmh[r + 1], w2 = wmh[r + 2], w3 = wmh[r + 3];
      const float w4 = wmh[r + 4], w5 = wmh[r + 5], w6 = wmh[r + 6], w7 = wmh[r + 7];
      acc.x = fmaf(w0, v0.x, acc.x); acc.y = fmaf(w0, v0.y, acc.y);
      acc.z = fmaf(w0, v0.z, acc.z); acc.w = fmaf(w0, v0.w, acc.w);
      acc.x = fmaf(w1, v1.x, acc.x); acc.y = fmaf(w1, v1.y, acc.y);
      acc.z = fmaf(w1, v1.z, acc.z); acc.w = fmaf(w1, v1.w, acc.w);
      acc.x = fmaf(w2, v2.x, acc.x); acc.y = fmaf(w2, v2.y, acc.y);
      acc.z = fmaf(w2, v2.z, acc.z); acc.w = fmaf(w2, v2.w, acc.w);
      acc.x = fmaf(w3, v3.x, acc.x); acc.y = fmaf(w3, v3.y, acc.y);
      acc.z = fmaf(w3, v3.z, acc.z); acc.w = fmaf(w3, v3.w, acc.w);
      acc.x = fmaf(w4, v4.x, acc.x); acc.y = fmaf(w4, v4.y, acc.y);
      acc.z = fmaf(w4, v4.z, acc.z); acc.w = fmaf(w4, v4.w, acc.w);
      acc.x = fmaf(w5, v5.x, acc.x); acc.y = fmaf(w5, v5.y, acc.y);
      acc.z = fmaf(w5, v5.z, acc.z); acc.w = fmaf(w5, v5.w, acc.w);
      acc.x = fmaf(w6, v6.x, acc.x); acc.y = fmaf(w6, v6.y, acc.y);
      acc.z = fmaf(w6, v6.z, acc.z); acc.w = fmaf(w6, v6.w, acc.w);
      acc.x = fmaf(w7, v7.x, acc.x); acc.y = fmaf(w7, v7.y, acc.y);
      acc.z = fmaf(w7, v7.z, acc.z); acc.w = fmaf(w7, v7.w, acc.w);
    }
    const int k0 = chunk * 512 + lt * 4;
    float* wf = ws + WS_WF;
    wf[(size_t)(k0 + 0) * 128 + eh] = acc.x;
    wf[(size_t)(k0 + 1) * 128 + eh] = acc.y;
    wf[(size_t)(k0 + 2) * 128 + eh] = acc.z;
    wf[(size_t)(k0 + 3) * 128 + eh] = acc.w;
  } else {
    // ---------------- target conv + BN path (VALU-bound) ----------------
    const int cb = bid;
    const int coblk = cb >> 4;            // 16 co-blocks of 16 channels
    const int pxblk = cb & 15;            // 16 row-pair blocks
    const int co0 = coblk * 16;
    const int y0 = pxblk * 2;
    const int wave = tid >> 6, lane = tid & 63;
    const int y = y0 + (lane >> 5), x = lane & 31;
    int coA = co0 + wave * 4;
    coA = __builtin_amdgcn_readfirstlane(coA);   // force scalar weight loads
    const float* tfp = ws + WS_TFP;
    const float* wT = ws + WS_WT;
    const float* tfpc = tfp + y * 34 + x;
    const float* wpc = wT + coA * 9;

    float acc[4] = {0.f, 0.f, 0.f, 0.f};
    float b0[9], b1[9], w0_[36], w1_[36];
    #pragma unroll
    for (int k = 0; k < 9; k++) b0[k] = tfpc[(k / 3) * 34 + (k % 3)];
    #pragma unroll
    for (int k = 0; k < 36; k++) w0_[k] = wpc[k];

    for (int ci = 0; ci < 512; ci += 2) {
      const float* tn = tfpc + (size_t)(ci + 1) * 1156;
      const float* wn = wpc + (size_t)(ci + 1) * 2304;
      #pragma unroll
      for (int k = 0; k < 9; k++) b1[k] = tn[(k / 3) * 34 + (k % 3)];
      #pragma unroll
      for (int k = 0; k < 36; k++) w1_[k] = wn[k];
      #pragma unroll
      for (int c = 0; c < 4; c++)
        #pragma unroll
        for (int k = 0; k < 9; k++)
          acc[c] = fmaf(w0_[c * 9 + k], b0[k], acc[c]);
      if (ci + 2 < 512) {
        const float* t2 = tfpc + (size_t)(ci + 2) * 1156;
        const float* w2 = wpc + (size_t)(ci + 2) * 2304;
        #pragma unroll
        for (int k = 0; k < 9; k++) b0[k] = t2[(k / 3) * 34 + (k % 3)];
        #pragma unroll
        for (int k = 0; k < 36; k++) w0_[k] = w2[k];
      }
      #pragma unroll
      for (int c = 0; c < 4; c++)
        #pragma unroll
        for (int k = 0; k < 9; k++)
          acc[c] = fmaf(w1_[c * 9 + k], b1[k], acc[c]);
    }
    float* tP = ws + WS_TP;
    #pragma unroll
    for (int c = 0; c < 4; c++) {
      const int co = coA + c;
      const float sc = gamma[co] * rsqrtf(var[co] + 1e-5f);
      float t = (acc[c] + btgt[co] - mean[co]) * sc + beta[co];
      t *= 0.1f;                          // fold the 0.1 xcorr factor into t'
      tP[co * 1520 + (y + 3) * 40 + (x + 3)] = t;
    }
  }
}

__global__ __launch_bounds__(256) void k2_z2(
    const float* __restrict__ zfeat,    // template_feat 2*512*49
    float* ws)
{
  __shared__ float Tl[50][144];
  const int tid = threadIdx.x;
  const int n = blockIdx.x >> 5, kc = blockIdx.x & 31;
  const int ci0 = kc * 16;
  // stage im2col rows of the template (zero-padded 3x3 halo), k-local = (ci-ci0)*9+pq
  for (int idx = tid; idx < 7200; idx += 256) {
    const int uv = idx / 144, kk = idx % 144;
    float v = 0.f;
    if (uv < 49) {
      const int u = uv / 7, vv = uv % 7;
      const int ci = ci0 + kk / 9, pq = kk % 9;
      const int p = pq / 3, q = pq % 3;
      const int yy = u + p - 1, xx = vv + q - 1;
      if (yy >= 0 && yy < 7 && xx >= 0 && xx < 7)
        v = zfeat[n * 25088 + ci * 49 + yy * 7 + xx];
    }
    Tl[uv][kk] = v;
  }
  __syncthreads();
  const int ehq = tid & 31, uvg = tid >> 5;
  const int eh0 = ehq * 4;
  const int uv0 = (uvg == 0) ? 0 : uvg * 6 + 1;
  const float* wf = ws + WS_WF;
  float4 acc[7];
  #pragma unroll
  for (int i = 0; i < 7; i++) acc[i] = make_float4(0.f, 0.f, 0.f, 0.f);
  for (int g = 0; g < 36; g++) {
    const float* wr = wf + (size_t)(ci0 * 9 + g * 4) * 128 + eh0;
    const float4 wv0 = *(const float4*)(wr);
    const float4 wv1 = *(const float4*)(wr + 128);
    const float4 wv2 = *(const float4*)(wr + 256);
    const float4 wv3 = *(const float4*)(wr + 384);
    #pragma unroll
    for (int uu = 0; uu < 7; uu++) {
      const float4 t4 = *(const float4*)(&Tl[uv0 + uu][g * 4]);
      acc[uu].x = fmaf(t4.x, wv0.x, fmaf(t4.y, wv1.x, fmaf(t4.z, wv2.x, fmaf(t4.w, wv3.x, acc[uu].x))));
      acc[uu].y = fmaf(t4.x, wv0.y, fmaf(t4.y, wv1.y, fmaf(t4.z, wv2.y, fmaf(t4.w, wv3.y, acc[uu].y))));
      acc[uu].z = fmaf(t4.x, wv0.z, fmaf(t4.y, wv1.z, fmaf(t4.z, wv2.z, fmaf(t4.w, wv3.z, acc[uu].z))));
      acc[uu].w = fmaf(t4.x, wv0.w, fmaf(t4.y, wv1.w, fmaf(t4.z, wv2.w, fmaf(t4.w, wv3.w, acc[uu].w))));
    }
  }
  float* z2p = ws + WS_Z2P;
  #pragma unroll
  for (int uu = 0; uu < 7; uu++) {
    const int uv = uv0 + uu;
    if (uv <= 48)   // overlapping uv written twice with identical values (benign)
      *(float4*)(z2p + ((size_t)((n * 32 + kc) * 49 + uv)) * 128 + eh0) = acc[uu];
  }
}

__global__ __launch_bounds__(128) void k3_merged(float* ws)
{
  __shared__ float Z2s[16][7][8];
  const int tid = threadIdx.x;
  const int bid = blockIdx.x;
  const int n = bid >> 7, rest = bid & 127;
  const int ec = rest >> 4, hq = rest & 15;
  const int c0 = ec * 16, h0 = hq * 2;
  const float* z2p = ws + WS_Z2P;
  const float* bf = ws + WS_BF;
  // reduce the 32 K-split partials (+ Bfold) for this block's 16 channels
  for (int idx = tid; idx < 784; idx += 128) {
    const int cl = idx & 15, uv = idx >> 4;
    float s = bf[c0 + cl];
    const float* p = z2p + (size_t)(n * 1568 + uv) * 128 + (c0 + cl);
    #pragma unroll 8
    for (int kc = 0; kc < 32; kc++) s += p[(size_t)kc * 6272];
    Z2s[cl][uv / 7][uv % 7] = s;
  }
  for (int idx = tid; idx < 112; idx += 128)
    Z2s[idx / 7][idx % 7][7] = 0.f;   // 8th lane of v-dim = 0
  __syncthreads();

  const int e = tid >> 4, row = (tid >> 3) & 1, wq = tid & 7;
  const int w0 = wq * 4;
  const float* tP = ws + WS_TP;
  float acc[4] = {0.f, 0.f, 0.f, 0.f};
  #pragma unroll
  for (int h128 = 0; h128 < 2; h128++) {
    const int cl = 2 * e + h128;
    const float* tc = tP + (size_t)(128 * n + c0 + cl) * 1520;
    #pragma unroll
    for (int u = 0; u < 7; u++) {
      const float* trow = tc + (h0 + row + u) * 40 + w0;
      float tw[12];
      *(float4*)&tw[0] = *(const float4*)(trow);
      *(float4*)&tw[4] = *(const float4*)(trow + 4);
      *(float4*)&tw[8] = *(const float4*)(trow + 8);
      float z[8];
      *(float4*)&z[0] = *(const float4*)&Z2s[cl][u][0];
      *(float4*)&z[4] = *(const float4*)&Z2s[cl][u][4];
      #pragma unroll
      for (int px = 0; px < 4; px++)
        #pragma unroll
        for (int v = 0; v < 8; v++)
          acc[px] = fmaf(z[v], tw[px + v], acc[px]);
    }
  }
  float* mrg = ws + WS_MRG;
  *(float4*)(mrg + (size_t)(((n * 64 + ec * 8 + e) * 32) + h0 + row) * 32 + w0) =
      make_float4(acc[0], acc[1], acc[2], acc[3]);
}

__global__ __launch_bounds__(256) void k4_heads(
    const float* __restrict__ cb,
    const float* __restrict__ wcls, const float* __restrict__ bcls,
    const float* __restrict__ wbox, const float* __restrict__ bbox,
    float* ws, float* __restrict__ out)
{
  __shared__ float mrg_l[32][66];   // [w][e], padded for bank spread
  __shared__ float wcb_l[54][64];
  __shared__ float bias_l[54];
  __shared__ float logits[18][32];
  const int tid = threadIdx.x;
  const int n = blockIdx.x >> 5, h = blockIdx.x & 31;
  const float* mrg = ws + WS_MRG;
  for (int idx = tid; idx < 2048; idx += 256) {
    const int e = idx >> 5, w = idx & 31;
    mrg_l[w][e] = mrg[(size_t)(((n * 64 + e) * 32) + h) * 32 + w] + cb[e];
  }
  for (int idx = tid; idx < 3456; idx += 256) {
    const int ch = idx >> 6, e = idx & 63;
    wcb_l[ch][e] = (ch < 18) ? wcls[ch * 64 + e] : wbox[(ch - 18) * 64 + e];
  }
  if (tid < 54) bias_l[tid] = (tid < 18) ? bcls[tid] : bbox[tid - 18];
  __syncthreads();

  const int w = tid & 31, chg = tid >> 5;
  const int cnt = (chg < 6) ? 7 : 6;
  float acc[7] = {0.f, 0.f, 0.f, 0.f, 0.f, 0.f, 0.f};
  for (int e2 = 0; e2 < 32; e2++) {
    const float2 m2 = *(const float2*)&mrg_l[w][e2 * 2];
    #pragma unroll
    for (int i = 0; i < 7; i++) {
      if (i < cnt) {
        const int ch = chg + 8 * i;
        const float2 wv = *(const float2*)&wcb_l[ch][e2 * 2];
        acc[i] = fmaf(m2.x, wv.x, acc[i]);
        acc[i] = fmaf(m2.y, wv.y, acc[i]);
      }
    }
  }
  #pragma unroll
  for (int i = 0; i < 7; i++) {
    if (i < cnt) {
      const int ch = chg + 8 * i;
      const float v = acc[i] + bias_l[ch];
      if (ch < 18) logits[ch][w] = v;
      else out[36864 + n * 36864 + (ch - 18) * 1024 + h * 32 + w] = v;
    }
  }
  __syncthreads();
  for (int idx = tid; idx < 576; idx += 256) {
    const int ch = idx >> 5, w2 = idx & 31;
    const float a = logits[ch][w2];
    const float b = logits[(ch + 9) % 18][w2];
    const float m = fmaxf(a, b);
    const float ea = expf(a - m), eb = expf(b - m);
    out[n * 18432 + ch * 1024 + h * 32 + w2] = ea / (ea + eb);
  }
}

extern "C" void kernel_launch(void* const* d_in, const int* in_sizes, int n_in,
                              void* d_out, int out_size, void* d_ws, size_t ws_size,
                              hipStream_t stream) {
  (void)in_sizes; (void)n_in; (void)out_size; (void)ws_size;
  const float* target_feat   = (const float*)d_in[0];
  const float* template_feat = (const float*)d_in[1];
  const float* w_target      = (const float*)d_in[2];
  const float* b_target      = (const float*)d_in[3];
  const float* bn_gamma      = (const float*)d_in[4];
  const float* bn_beta       = (const float*)d_in[5];
  const float* bn_mean       = (const float*)d_in[6];
  const float* bn_var        = (const float*)d_in[7];
  const float* w_template    = (const float*)d_in[8];
  const float* b_template    = (const float*)d_in[9];
  const float* w_merge       = (const float*)d_in[10];
  const float* corr_bias     = (const float*)d_in[11];
  const float* w_cls         = (const float*)d_in[12];
  const float* b_cls         = (const float*)d_in[13];
  const float* w_box         = (const float*)d_in[14];
  const float* b_box         = (const float*)d_in[15];
  float* ws = (float*)d_ws;
  float* out = (float*)d_out;

  hipLaunchKernelGGL(k0_prep, dim3(2048), dim3(256), 0, stream,
                     target_feat, w_target, w_merge, b_template, ws);
  hipLaunchKernelGGL(k1_fold_conv, dim3(832), dim3(256), 0, stream,
                     w_template, w_merge, b_target,
                     bn_gamma, bn_beta, bn_mean, bn_var, ws);
  hipLaunchKernelGGL(k2_z2, dim3(64), dim3(256), 0, stream,
                     template_feat, ws);
  hipLaunchKernelGGL(k3_merged, dim3(256), dim3(128), 0, stream, ws);
  hipLaunchKernelGGL(k4_heads, dim3(64), dim3(256), 0, stream,
                     corr_bias, w_cls, b_cls, w_box, b_box, ws, out);
}

// Round 5
// 231.476 us; speedup vs baseline: 1.3820x; 1.3820x over previous
//
#include <hip/hip_runtime.h>
#include <math.h>

// ---------------------------------------------------------------------------
// SiameseRPN one-branch, round 5: k1 split into k_fold + k_conv.
//  k_fold: WfoldT[4608][128] = sum over 128-row groups of wm[co&255]*wtpl[co][k]
//          1152 blocks (g=co>>7 x 9 col-chunks), contiguous row streaming,
//          8 float4 loads in flight, no LDS in K-loop.         [HBM-bound]
//  k0    : pad target_feat -> tfp[512][34][34]; zero tP[256][38][40]; Bfold.
//  k_conv: 3x3 conv target + BN + 0.1, thread=4co x 2px, in-block K-split x4
//          (512 thr = 4 ks-groups), weights as float4 broadcasts from w_target,
//          LDS ks-reduce -> tP interior.                       [VALU-bound]
//  k2/k3/k4 unchanged from round 2 (verified, microseconds).
// Workspace: 3,283,072 floats = 13.2 MB (layout unchanged; WT region unused)
// ---------------------------------------------------------------------------

#define WS_TFP 0            // 512*34*34      = 591872
#define WS_WT  591872       // (unused this round)
#define WS_TP  1771520      // 256*38*40      = 389120
#define WS_WF  2160640      // 4608*128       = 589824
#define WS_BF  2750464      // 128
#define WS_Z2P 2750592      // 2*32*49*128    = 401408
#define WS_MRG 3152000      // 2*64*32*32     = 131072

typedef float f4u __attribute__((ext_vector_type(4), aligned(4)));

__global__ __launch_bounds__(256) void k_fold(
    const float* __restrict__ wtpl,    // w_template 16384*4608
    const float* __restrict__ wm,      // w_merge_cls 256
    float* ws)
{
  // g = eh = co>>7 (0..127); chunk = 512-float column window (9 of them)
  const int g = blockIdx.x / 9, chunk = blockIdx.x % 9;
  const int tid = threadIdx.x;
  const int t = tid & 127, grp = tid >> 7;   // grp: rows 0-63 / 64-127
  const int c0 = chunk * 512 + t * 4;
  const float* base = wtpl + (size_t)(g * 128 + grp * 64) * 4608 + c0;
  const float* wmb = wm + (g & 1) * 128 + grp * 64;
  float4 acc = make_float4(0.f, 0.f, 0.f, 0.f);
  for (int r = 0; r < 64; r += 8) {
    const float4 v0 = *(const float4*)(base + (size_t)(r + 0) * 4608);
    const float4 v1 = *(const float4*)(base + (size_t)(r + 1) * 4608);
    const float4 v2 = *(const float4*)(base + (size_t)(r + 2) * 4608);
    const float4 v3 = *(const float4*)(base + (size_t)(r + 3) * 4608);
    const float4 v4 = *(const float4*)(base + (size_t)(r + 4) * 4608);
    const float4 v5 = *(const float4*)(base + (size_t)(r + 5) * 4608);
    const float4 v6 = *(const float4*)(base + (size_t)(r + 6) * 4608);
    const float4 v7 = *(const float4*)(base + (size_t)(r + 7) * 4608);
    const float w0 = wmb[r + 0], w1 = wmb[r + 1], w2 = wmb[r + 2], w3 = wmb[r + 3];
    const float w4 = wmb[r + 4], w5 = wmb[r + 5], w6 = wmb[r + 6], w7 = wmb[r + 7];
    acc.x = fmaf(w0, v0.x, acc.x); acc.y = fmaf(w0, v0.y, acc.y);
    acc.z = fmaf(w0, v0.z, acc.z); acc.w = fmaf(w0, v0.w, acc.w);
    acc.x = fmaf(w1, v1.x, acc.x); acc.y = fmaf(w1, v1.y, acc.y);
    acc.z = fmaf(w1, v1.z, acc.z); acc.w = fmaf(w1, v1.w, acc.w);
    acc.x = fmaf(w2, v2.x, acc.x); acc.y = fmaf(w2, v2.y, acc.y);
    acc.z = fmaf(w2, v2.z, acc.z); acc.w = fmaf(w2, v2.w, acc.w);
    acc.x = fmaf(w3, v3.x, acc.x); acc.y = fmaf(w3, v3.y, acc.y);
    acc.z = fmaf(w3, v3.z, acc.z); acc.w = fmaf(w3, v3.w, acc.w);
    acc.x = fmaf(w4, v4.x, acc.x); acc.y = fmaf(w4, v4.y, acc.y);
    acc.z = fmaf(w4, v4.z, acc.z); acc.w = fmaf(w4, v4.w, acc.w);
    acc.x = fmaf(w5, v5.x, acc.x); acc.y = fmaf(w5, v5.y, acc.y);
    acc.z = fmaf(w5, v5.z, acc.z); acc.w = fmaf(w5, v5.w, acc.w);
    acc.x = fmaf(w6, v6.x, acc.x); acc.y = fmaf(w6, v6.y, acc.y);
    acc.z = fmaf(w6, v6.z, acc.z); acc.w = fmaf(w6, v6.w, acc.w);
    acc.x = fmaf(w7, v7.x, acc.x); acc.y = fmaf(w7, v7.y, acc.y);
    acc.z = fmaf(w7, v7.z, acc.z); acc.w = fmaf(w7, v7.w, acc.w);
  }
  __shared__ float4 red[128];
  if (grp) red[t] = acc;
  __syncthreads();
  if (!grp) {
    const float4 o = red[t];
    acc.x += o.x; acc.y += o.y; acc.z += o.z; acc.w += o.w;
    float* wf = ws + WS_WF;
    wf[(size_t)(c0 + 0) * 128 + g] = acc.x;
    wf[(size_t)(c0 + 1) * 128 + g] = acc.y;
    wf[(size_t)(c0 + 2) * 128 + g] = acc.z;
    wf[(size_t)(c0 + 3) * 128 + g] = acc.w;
  }
}

__global__ __launch_bounds__(256) void k0_prep(
    const float* __restrict__ tfeat,   // target_feat 512*32*32
    const float* __restrict__ wm,      // w_merge_cls 256
    const float* __restrict__ btpl,    // b_template 16384
    float* ws)
{
  const int N0 = 591872, N2 = 389120;
  const int total = N0 + N2;
  for (int idx = blockIdx.x * 256 + threadIdx.x; idx < total + 128; idx += gridDim.x * 256) {
    if (idx < N0) {
      int ci = idx / 1156, r = idx % 1156;
      int yy = r / 34, xx = r % 34;
      float v = 0.f;
      if (yy >= 1 && yy <= 32 && xx >= 1 && xx <= 32)
        v = tfeat[ci * 1024 + (yy - 1) * 32 + (xx - 1)];
      ws[WS_TFP + idx] = v;
    } else if (idx < total) {
      ws[WS_TP + (idx - N0)] = 0.f;
    } else {
      const int eh = idx - total;
      const int e = eh >> 1, h = eh & 1;
      const float* wmp = wm + h * 128;
      const float* bp = btpl + e * 256 + h * 128;
      float s = 0.f;
      for (int cl = 0; cl < 128; cl++) s = fmaf(wmp[cl], bp[cl], s);
      ws[WS_BF + eh] = s;
    }
  }
}

__global__ __launch_bounds__(512) void k_conv(
    const float* __restrict__ wtgt,    // w_target 256*512*9
    const float* __restrict__ btgt,
    const float* __restrict__ gamma, const float* __restrict__ beta,
    const float* __restrict__ mean, const float* __restrict__ var,
    float* ws)
{
  // block tile: 16 co x (2 rows x 32 cols); 512 thr = 4 K-split groups x 128
  // thread: 4 co x 2 px over 128 ci
  __shared__ float red[3][128][8];
  const int tid = threadIdx.x;
  const int ks = tid >> 7;
  const int sub = tid & 127;
  const int cog = sub >> 5;
  const int pxg = sub & 31;
  const int row = pxg >> 4;
  const int x0 = (pxg & 15) * 2;
  const int co0 = (blockIdx.x >> 4) * 16 + cog * 4;
  const int y = (blockIdx.x & 15) * 2 + row;
  const float* tfp = ws + WS_TFP;

  float acc[4][2] = {{0.f, 0.f}, {0.f, 0.f}, {0.f, 0.f}, {0.f, 0.f}};
  for (int i = 0; i < 128; i++) {
    const int ci = ks * 128 + i;
    const float* tin = tfp + (size_t)ci * 1156 + y * 34 + x0;
    const f4u p0 = *(const f4u*)(tin);
    const f4u p1 = *(const f4u*)(tin + 34);
    const f4u p2 = *(const f4u*)(tin + 68);
    #pragma unroll
    for (int c = 0; c < 4; c++) {
      const float* wr = wtgt + (size_t)(co0 + c) * 4608 + ci * 9;
      const f4u wa = *(const f4u*)(wr);
      const f4u wb = *(const f4u*)(wr + 4);
      const float w8 = wr[8];
      acc[c][0] += wa.x * p0.x + wa.y * p0.y + wa.z * p0.z
                 + wa.w * p1.x + wb.x * p1.y + wb.y * p1.z
                 + wb.z * p2.x + wb.w * p2.y + w8 * p2.z;
      acc[c][1] += wa.x * p0.y + wa.y * p0.z + wa.z * p0.w
                 + wa.w * p1.y + wb.x * p1.z + wb.y * p1.w
                 + wb.z * p2.y + wb.w * p2.z + w8 * p2.w;
    }
  }
  if (ks) {
    #pragma unroll
    for (int c = 0; c < 4; c++) {
      red[ks - 1][sub][c * 2 + 0] = acc[c][0];
      red[ks - 1][sub][c * 2 + 1] = acc[c][1];
    }
  }
  __syncthreads();
  if (ks == 0) {
    float* tP = ws + WS_TP;
    #pragma unroll
    for (int c = 0; c < 4; c++) {
      const int co = co0 + c;
      const float sc = gamma[co] * rsqrtf(var[co] + 1e-5f);
      #pragma unroll
      for (int p = 0; p < 2; p++) {
        float a = acc[c][p] + red[0][sub][c * 2 + p]
                            + red[1][sub][c * 2 + p]
                            + red[2][sub][c * 2 + p];
        float t = (a + btgt[co] - mean[co]) * sc + beta[co];
        t *= 0.1f;
        tP[co * 1520 + (y + 3) * 40 + (x0 + p + 3)] = t;
      }
    }
  }
}

__global__ __launch_bounds__(256) void k2_z2(
    const float* __restrict__ zfeat,    // template_feat 2*512*49
    float* ws)
{
  __shared__ float Tl[50][144];
  const int tid = threadIdx.x;
  const int n = blockIdx.x >> 5, kc = blockIdx.x & 31;
  const int ci0 = kc * 16;
  for (int idx = tid; idx < 7200; idx += 256) {
    const int uv = idx / 144, kk = idx % 144;
    float v = 0.f;
    if (uv < 49) {
      const int u = uv / 7, vv = uv % 7;
      const int ci = ci0 + kk / 9, pq = kk % 9;
      const int p = pq / 3, q = pq % 3;
      const int yy = u + p - 1, xx = vv + q - 1;
      if (yy >= 0 && yy < 7 && xx >= 0 && xx < 7)
        v = zfeat[n * 25088 + ci * 49 + yy * 7 + xx];
    }
    Tl[uv][kk] = v;
  }
  __syncthreads();
  const int ehq = tid & 31, uvg = tid >> 5;
  const int eh0 = ehq * 4;
  const int uv0 = (uvg == 0) ? 0 : uvg * 6 + 1;
  const float* wf = ws + WS_WF;
  float4 acc[7];
  #pragma unroll
  for (int i = 0; i < 7; i++) acc[i] = make_float4(0.f, 0.f, 0.f, 0.f);
  for (int g = 0; g < 36; g++) {
    const float* wr = wf + (size_t)(ci0 * 9 + g * 4) * 128 + eh0;
    const float4 wv0 = *(const float4*)(wr);
    const float4 wv1 = *(const float4*)(wr + 128);
    const float4 wv2 = *(const float4*)(wr + 256);
    const float4 wv3 = *(const float4*)(wr + 384);
    #pragma unroll
    for (int uu = 0; uu < 7; uu++) {
      const float4 t4 = *(const float4*)(&Tl[uv0 + uu][g * 4]);
      acc[uu].x = fmaf(t4.x, wv0.x, fmaf(t4.y, wv1.x, fmaf(t4.z, wv2.x, fmaf(t4.w, wv3.x, acc[uu].x))));
      acc[uu].y = fmaf(t4.x, wv0.y, fmaf(t4.y, wv1.y, fmaf(t4.z, wv2.y, fmaf(t4.w, wv3.y, acc[uu].y))));
      acc[uu].z = fmaf(t4.x, wv0.z, fmaf(t4.y, wv1.z, fmaf(t4.z, wv2.z, fmaf(t4.w, wv3.z, acc[uu].z))));
      acc[uu].w = fmaf(t4.x, wv0.w, fmaf(t4.y, wv1.w, fmaf(t4.z, wv2.w, fmaf(t4.w, wv3.w, acc[uu].w))));
    }
  }
  float* z2p = ws + WS_Z2P;
  #pragma unroll
  for (int uu = 0; uu < 7; uu++) {
    const int uv = uv0 + uu;
    if (uv <= 48)
      *(float4*)(z2p + ((size_t)((n * 32 + kc) * 49 + uv)) * 128 + eh0) = acc[uu];
  }
}

__global__ __launch_bounds__(128) void k3_merged(float* ws)
{
  __shared__ float Z2s[16][7][8];
  const int tid = threadIdx.x;
  const int bid = blockIdx.x;
  const int n = bid >> 7, rest = bid & 127;
  const int ec = rest >> 4, hq = rest & 15;
  const int c0 = ec * 16, h0 = hq * 2;
  const float* z2p = ws + WS_Z2P;
  const float* bf = ws + WS_BF;
  for (int idx = tid; idx < 784; idx += 128) {
    const int cl = idx & 15, uv = idx >> 4;
    float s = bf[c0 + cl];
    const float* p = z2p + (size_t)(n * 1568 + uv) * 128 + (c0 + cl);
    #pragma unroll 8
    for (int kc = 0; kc < 32; kc++) s += p[(size_t)kc * 6272];
    Z2s[cl][uv / 7][uv % 7] = s;
  }
  for (int idx = tid; idx < 112; idx += 128)
    Z2s[idx / 7][idx % 7][7] = 0.f;
  __syncthreads();

  const int e = tid >> 4, row = (tid >> 3) & 1, wq = tid & 7;
  const int w0 = wq * 4;
  const float* tP = ws + WS_TP;
  float acc[4] = {0.f, 0.f, 0.f, 0.f};
  #pragma unroll
  for (int h128 = 0; h128 < 2; h128++) {
    const int cl = 2 * e + h128;
    const float* tc = tP + (size_t)(128 * n + c0 + cl) * 1520;
    #pragma unroll
    for (int u = 0; u < 7; u++) {
      const float* trow = tc + (h0 + row + u) * 40 + w0;
      float tw[12];
      *(float4*)&tw[0] = *(const float4*)(trow);
      *(float4*)&tw[4] = *(const float4*)(trow + 4);
      *(float4*)&tw[8] = *(const float4*)(trow + 8);
      float z[8];
      *(float4*)&z[0] = *(const float4*)&Z2s[cl][u][0];
      *(float4*)&z[4] = *(const float4*)&Z2s[cl][u][4];
      #pragma unroll
      for (int px = 0; px < 4; px++)
        #pragma unroll
        for (int v = 0; v < 8; v++)
          acc[px] = fmaf(z[v], tw[px + v], acc[px]);
    }
  }
  float* mrg = ws + WS_MRG;
  *(float4*)(mrg + (size_t)(((n * 64 + ec * 8 + e) * 32) + h0 + row) * 32 + w0) =
      make_float4(acc[0], acc[1], acc[2], acc[3]);
}

__global__ __launch_bounds__(256) void k4_heads(
    const float* __restrict__ cb,
    const float* __restrict__ wcls, const float* __restrict__ bcls,
    const float* __restrict__ wbox, const float* __restrict__ bbox,
    float* ws, float* __restrict__ out)
{
  __shared__ float mrg_l[32][66];
  __shared__ float wcb_l[54][64];
  __shared__ float bias_l[54];
  __shared__ float logits[18][32];
  const int tid = threadIdx.x;
  const int n = blockIdx.x >> 5, h = blockIdx.x & 31;
  const float* mrg = ws + WS_MRG;
  for (int idx = tid; idx < 2048; idx += 256) {
    const int e = idx >> 5, w = idx & 31;
    mrg_l[w][e] = mrg[(size_t)(((n * 64 + e) * 32) + h) * 32 + w] + cb[e];
  }
  for (int idx = tid; idx < 3456; idx += 256) {
    const int ch = idx >> 6, e = idx & 63;
    wcb_l[ch][e] = (ch < 18) ? wcls[ch * 64 + e] : wbox[(ch - 18) * 64 + e];
  }
  if (tid < 54) bias_l[tid] = (tid < 18) ? bcls[tid] : bbox[tid - 18];
  __syncthreads();

  const int w = tid & 31, chg = tid >> 5;
  const int cnt = (chg < 6) ? 7 : 6;
  float acc[7] = {0.f, 0.f, 0.f, 0.f, 0.f, 0.f, 0.f};
  for (int e2 = 0; e2 < 32; e2++) {
    const float2 m2 = *(const float2*)&mrg_l[w][e2 * 2];
    #pragma unroll
    for (int i = 0; i < 7; i++) {
      if (i < cnt) {
        const int ch = chg + 8 * i;
        const float2 wv = *(const float2*)&wcb_l[ch][e2 * 2];
        acc[i] = fmaf(m2.x, wv.x, acc[i]);
        acc[i] = fmaf(m2.y, wv.y, acc[i]);
      }
    }
  }
  #pragma unroll
  for (int i = 0; i < 7; i++) {
    if (i < cnt) {
      const int ch = chg + 8 * i;
      const float v = acc[i] + bias_l[ch];
      if (ch < 18) logits[ch][w] = v;
      else out[36864 + n * 36864 + (ch - 18) * 1024 + h * 32 + w] = v;
    }
  }
  __syncthreads();
  for (int idx = tid; idx < 576; idx += 256) {
    const int ch = idx >> 5, w2 = idx & 31;
    const float a = logits[ch][w2];
    const float b = logits[(ch + 9) % 18][w2];
    const float m = fmaxf(a, b);
    const float ea = expf(a - m), eb = expf(b - m);
    out[n * 18432 + ch * 1024 + h * 32 + w2] = ea / (ea + eb);
  }
}

extern "C" void kernel_launch(void* const* d_in, const int* in_sizes, int n_in,
                              void* d_out, int out_size, void* d_ws, size_t ws_size,
                              hipStream_t stream) {
  (void)in_sizes; (void)n_in; (void)out_size; (void)ws_size;
  const float* target_feat   = (const float*)d_in[0];
  const float* template_feat = (const float*)d_in[1];
  const float* w_target      = (const float*)d_in[2];
  const float* b_target      = (const float*)d_in[3];
  const float* bn_gamma      = (const float*)d_in[4];
  const float* bn_beta       = (const float*)d_in[5];
  const float* bn_mean       = (const float*)d_in[6];
  const float* bn_var        = (const float*)d_in[7];
  const float* w_template    = (const float*)d_in[8];
  const float* b_template    = (const float*)d_in[9];
  const float* w_merge       = (const float*)d_in[10];
  const float* corr_bias     = (const float*)d_in[11];
  const float* w_cls         = (const float*)d_in[12];
  const float* b_cls         = (const float*)d_in[13];
  const float* w_box         = (const float*)d_in[14];
  const float* b_box         = (const float*)d_in[15];
  float* ws = (float*)d_ws;
  float* out = (float*)d_out;

  hipLaunchKernelGGL(k_fold, dim3(1152), dim3(256), 0, stream,
                     w_template, w_merge, ws);
  hipLaunchKernelGGL(k0_prep, dim3(2048), dim3(256), 0, stream,
                     target_feat, w_merge, b_template, ws);
  hipLaunchKernelGGL(k_conv, dim3(256), dim3(512), 0, stream,
                     w_target, b_target, bn_gamma, bn_beta, bn_mean, bn_var, ws);
  hipLaunchKernelGGL(k2_z2, dim3(64), dim3(256), 0, stream,
                     template_feat, ws);
  hipLaunchKernelGGL(k3_merged, dim3(256), dim3(128), 0, stream, ws);
  hipLaunchKernelGGL(k4_heads, dim3(64), dim3(256), 0, stream,
                     corr_bias, w_cls, b_cls, w_box, b_box, ws, out);
}

// Round 7
// 229.722 us; speedup vs baseline: 1.3925x; 1.0076x over previous
//
#include <hip/hip_runtime.h>
#include <math.h>

// ---------------------------------------------------------------------------
// SiameseRPN one-branch, round 7 (= round 6 + macro fix):
//  k_fold: WFP[2][4608][128] partial fold of w_merge into w_template.
//          2304 blocks (128 g x 9 chunks x 2 halves), 16 float4 loads in
//          flight per wave, 2-way in-block LDS reduce.          [HBM-bound]
//  k0    : pad target_feat -> tfp[512][34][34]; zero tP[256][38][40]; Bfold.
//  k_conv: 3x3 conv partials, K-split x16 -> CVP[16][256][32][32]
//          2048 blocks x 256 thr, no LDS/sync, ~32 waves/CU TLP. [latency]
//  k_cred: sum 16 slabs + bias + BN + 0.1 -> tP interior.
//  k2    : Z2 partials (sums the two WFP slabs on load).
//  k3    : merged = sum t' * Z2.   k4: heads + softmax.
// Workspace: 6,887,552 floats = 27.6 MB.
// ---------------------------------------------------------------------------

#define WS_TFP 0            // 591872
#define WS_TP  591872       // 389120  -> 980992
#define WS_BF  980992       // 128     -> 981120
#define WS_WFP 981120       // 2*589824 -> 2160768
#define WS_Z2P 2160768      // 401408  -> 2562176
#define WS_MRG 2562176      // 131072  -> 2693248
#define WS_CVP 2693248      // 16*262144 -> 6887552
#define WFP_HALF 589824

typedef float f4u __attribute__((ext_vector_type(4), aligned(4)));

#define FMA4(ww, vv) \
  acc.x = fmaf(ww, (vv).x, acc.x); acc.y = fmaf(ww, (vv).y, acc.y); \
  acc.z = fmaf(ww, (vv).z, acc.z); acc.w = fmaf(ww, (vv).w, acc.w)

__global__ __launch_bounds__(256) void k_fold(
    const float* __restrict__ wtpl,    // w_template 16384*4608
    const float* __restrict__ wm,      // w_merge_cls 256
    float* ws)
{
  const int bid = blockIdx.x;
  const int g = bid / 18, rest = bid % 18;
  const int chunk = rest >> 1, half = rest & 1;
  const int tid = threadIdx.x;
  const int colv = tid & 127, rowg = tid >> 7;
  const int c0 = chunk * 512 + colv * 4;
  const int row0 = g * 128 + half * 64 + rowg * 32;
  const float* base = wtpl + (size_t)row0 * 4608 + c0;
  const float* wmb = wm + (g & 1) * 128 + half * 64 + rowg * 32;
  float4 acc = make_float4(0.f, 0.f, 0.f, 0.f);
  #pragma unroll
  for (int rr = 0; rr < 32; rr += 16) {
    const float* b = base + (size_t)rr * 4608;
    const float4 v0  = *(const float4*)(b);
    const float4 v1  = *(const float4*)(b + 1 * 4608);
    const float4 v2  = *(const float4*)(b + 2 * 4608);
    const float4 v3  = *(const float4*)(b + 3 * 4608);
    const float4 v4  = *(const float4*)(b + 4 * 4608);
    const float4 v5  = *(const float4*)(b + 5 * 4608);
    const float4 v6  = *(const float4*)(b + 6 * 4608);
    const float4 v7  = *(const float4*)(b + 7 * 4608);
    const float4 v8  = *(const float4*)(b + 8 * 4608);
    const float4 v9  = *(const float4*)(b + 9 * 4608);
    const float4 v10 = *(const float4*)(b + 10 * 4608);
    const float4 v11 = *(const float4*)(b + 11 * 4608);
    const float4 v12 = *(const float4*)(b + 12 * 4608);
    const float4 v13 = *(const float4*)(b + 13 * 4608);
    const float4 v14 = *(const float4*)(b + 14 * 4608);
    const float4 v15 = *(const float4*)(b + 15 * 4608);
    const float w0 = wmb[rr + 0],  w1 = wmb[rr + 1];
    const float w2 = wmb[rr + 2],  w3 = wmb[rr + 3];
    const float w4 = wmb[rr + 4],  w5 = wmb[rr + 5];
    const float w6 = wmb[rr + 6],  w7 = wmb[rr + 7];
    const float w8 = wmb[rr + 8],  w9 = wmb[rr + 9];
    const float w10 = wmb[rr + 10], w11 = wmb[rr + 11];
    const float w12 = wmb[rr + 12], w13 = wmb[rr + 13];
    const float w14 = wmb[rr + 14], w15 = wmb[rr + 15];
    FMA4(w0, v0);   FMA4(w1, v1);   FMA4(w2, v2);   FMA4(w3, v3);
    FMA4(w4, v4);   FMA4(w5, v5);   FMA4(w6, v6);   FMA4(w7, v7);
    FMA4(w8, v8);   FMA4(w9, v9);   FMA4(w10, v10); FMA4(w11, v11);
    FMA4(w12, v12); FMA4(w13, v13); FMA4(w14, v14); FMA4(w15, v15);
  }
  __shared__ float4 red[128];
  if (rowg) red[colv] = acc;
  __syncthreads();
  if (!rowg) {
    const float4 o = red[colv];
    acc.x += o.x; acc.y += o.y; acc.z += o.z; acc.w += o.w;
    float* wp = ws + WS_WFP + (size_t)half * WFP_HALF;
    wp[(size_t)(c0 + 0) * 128 + g] = acc.x;
    wp[(size_t)(c0 + 1) * 128 + g] = acc.y;
    wp[(size_t)(c0 + 2) * 128 + g] = acc.z;
    wp[(size_t)(c0 + 3) * 128 + g] = acc.w;
  }
}

__global__ __launch_bounds__(256) void k0_prep(
    const float* __restrict__ tfeat,   // target_feat 512*32*32
    const float* __restrict__ wm,      // w_merge_cls 256
    const float* __restrict__ btpl,    // b_template 16384
    float* ws)
{
  const int N0 = 591872, N2 = 389120;
  const int total = N0 + N2;
  for (int idx = blockIdx.x * 256 + threadIdx.x; idx < total + 128; idx += gridDim.x * 256) {
    if (idx < N0) {
      int ci = idx / 1156, r = idx % 1156;
      int yy = r / 34, xx = r % 34;
      float v = 0.f;
      if (yy >= 1 && yy <= 32 && xx >= 1 && xx <= 32)
        v = tfeat[ci * 1024 + (yy - 1) * 32 + (xx - 1)];
      ws[WS_TFP + idx] = v;
    } else if (idx < total) {
      ws[WS_TP + (idx - N0)] = 0.f;
    } else {
      const int eh = idx - total;
      const int e = eh >> 1, h = eh & 1;
      const float* wmp = wm + h * 128;
      const float* bp = btpl + e * 256 + h * 128;
      float s = 0.f;
      for (int cl = 0; cl < 128; cl++) s = fmaf(wmp[cl], bp[cl], s);
      ws[WS_BF + eh] = s;
    }
  }
}

__global__ __launch_bounds__(256) void k_conv(
    const float* __restrict__ wtgt,    // w_target 256*512*9
    float* ws)
{
  // grid: coblk(16) x pxblk(16) x ks(8); thread: ksub(2) x cog(4) x pxg(32)
  const int bid = blockIdx.x;
  const int coblk = bid >> 7, pxblk = (bid >> 3) & 15, ks = bid & 7;
  const int tid = threadIdx.x;
  const int ksub = tid >> 7, sub = tid & 127;
  const int cog = sub >> 5, pxg = sub & 31;
  const int row = pxg >> 4, x0 = (pxg & 15) * 2;
  const int y = pxblk * 2 + row;
  const int co0 = coblk * 16 + cog * 4;
  const int ci0 = ks * 64 + ksub * 32;
  const float* tfp = ws + WS_TFP;

  float acc[4][2] = {{0.f, 0.f}, {0.f, 0.f}, {0.f, 0.f}, {0.f, 0.f}};
  for (int i = 0; i < 32; i++) {
    const int ci = ci0 + i;
    const float* tin = tfp + (size_t)ci * 1156 + y * 34 + x0;
    const f4u p0 = *(const f4u*)(tin);
    const f4u p1 = *(const f4u*)(tin + 34);
    const f4u p2 = *(const f4u*)(tin + 68);
    #pragma unroll
    for (int c = 0; c < 4; c++) {
      const float* wr = wtgt + (size_t)(co0 + c) * 4608 + ci * 9;
      const f4u wa = *(const f4u*)(wr);
      const f4u wb = *(const f4u*)(wr + 4);
      const float w8 = wr[8];
      acc[c][0] += wa.x * p0.x + wa.y * p0.y + wa.z * p0.z
                 + wa.w * p1.x + wb.x * p1.y + wb.y * p1.z
                 + wb.z * p2.x + wb.w * p2.y + w8 * p2.z;
      acc[c][1] += wa.x * p0.y + wa.y * p0.z + wa.z * p0.w
                 + wa.w * p1.y + wb.x * p1.z + wb.y * p1.w
                 + wb.z * p2.y + wb.w * p2.z + w8 * p2.w;
    }
  }
  float* cvp = ws + WS_CVP + (size_t)(ks * 2 + ksub) * 262144;
  #pragma unroll
  for (int c = 0; c < 4; c++) {
    cvp[(co0 + c) * 1024 + y * 32 + x0 + 0] = acc[c][0];
    cvp[(co0 + c) * 1024 + y * 32 + x0 + 1] = acc[c][1];
  }
}

__global__ __launch_bounds__(256) void k_cred(
    const float* __restrict__ btgt,
    const float* __restrict__ gamma, const float* __restrict__ beta,
    const float* __restrict__ mean, const float* __restrict__ var,
    float* ws)
{
  const int co = blockIdx.x;
  const int tid = threadIdx.x;
  const float sc = gamma[co] * rsqrtf(var[co] + 1e-5f);
  const float off = btgt[co] - mean[co];
  const float bt = beta[co];
  const float* cvp = ws + WS_CVP + (size_t)co * 1024;
  float* tP = ws + WS_TP;
  #pragma unroll
  for (int k = 0; k < 4; k++) {
    const int j = k * 256 + tid;
    float s = 0.f;
    #pragma unroll
    for (int sl = 0; sl < 16; sl++) s += cvp[(size_t)sl * 262144 + j];
    const float t = ((s + off) * sc + bt) * 0.1f;
    const int yy = j >> 5, xx = j & 31;
    tP[co * 1520 + (yy + 3) * 40 + (xx + 3)] = t;
  }
}

__global__ __launch_bounds__(256) void k2_z2(
    const float* __restrict__ zfeat,    // template_feat 2*512*49
    float* ws)
{
  __shared__ float Tl[50][144];
  const int tid = threadIdx.x;
  const int n = blockIdx.x >> 5, kc = blockIdx.x & 31;
  const int ci0 = kc * 16;
  for (int idx = tid; idx < 7200; idx += 256) {
    const int uv = idx / 144, kk = idx % 144;
    float v = 0.f;
    if (uv < 49) {
      const int u = uv / 7, vv = uv % 7;
      const int ci = ci0 + kk / 9, pq = kk % 9;
      const int p = pq / 3, q = pq % 3;
      const int yy = u + p - 1, xx = vv + q - 1;
      if (yy >= 0 && yy < 7 && xx >= 0 && xx < 7)
        v = zfeat[n * 25088 + ci * 49 + yy * 7 + xx];
    }
    Tl[uv][kk] = v;
  }
  __syncthreads();
  const int ehq = tid & 31, uvg = tid >> 5;
  const int eh0 = ehq * 4;
  const int uv0 = (uvg == 0) ? 0 : uvg * 6 + 1;
  const float* wfp = ws + WS_WFP;
  float4 acc[7];
  #pragma unroll
  for (int i = 0; i < 7; i++) acc[i] = make_float4(0.f, 0.f, 0.f, 0.f);
  for (int g = 0; g < 36; g++) {
    const float* wr = wfp + (size_t)(ci0 * 9 + g * 4) * 128 + eh0;
    const float* wr2 = wr + WFP_HALF;
    float4 wv0 = *(const float4*)(wr);
    float4 wv1 = *(const float4*)(wr + 128);
    float4 wv2 = *(const float4*)(wr + 256);
    float4 wv3 = *(const float4*)(wr + 384);
    const float4 u0 = *(const float4*)(wr2);
    const float4 u1 = *(const float4*)(wr2 + 128);
    const float4 u2 = *(const float4*)(wr2 + 256);
    const float4 u3 = *(const float4*)(wr2 + 384);
    wv0.x += u0.x; wv0.y += u0.y; wv0.z += u0.z; wv0.w += u0.w;
    wv1.x += u1.x; wv1.y += u1.y; wv1.z += u1.z; wv1.w += u1.w;
    wv2.x += u2.x; wv2.y += u2.y; wv2.z += u2.z; wv2.w += u2.w;
    wv3.x += u3.x; wv3.y += u3.y; wv3.z += u3.z; wv3.w += u3.w;
    #pragma unroll
    for (int uu = 0; uu < 7; uu++) {
      const float4 t4 = *(const float4*)(&Tl[uv0 + uu][g * 4]);
      acc[uu].x = fmaf(t4.x, wv0.x, fmaf(t4.y, wv1.x, fmaf(t4.z, wv2.x, fmaf(t4.w, wv3.x, acc[uu].x))));
      acc[uu].y = fmaf(t4.x, wv0.y, fmaf(t4.y, wv1.y, fmaf(t4.z, wv2.y, fmaf(t4.w, wv3.y, acc[uu].y))));
      acc[uu].z = fmaf(t4.x, wv0.z, fmaf(t4.y, wv1.z, fmaf(t4.z, wv2.z, fmaf(t4.w, wv3.z, acc[uu].z))));
      acc[uu].w = fmaf(t4.x, wv0.w, fmaf(t4.y, wv1.w, fmaf(t4.z, wv2.w, fmaf(t4.w, wv3.w, acc[uu].w))));
    }
  }
  float* z2p = ws + WS_Z2P;
  #pragma unroll
  for (int uu = 0; uu < 7; uu++) {
    const int uv = uv0 + uu;
    if (uv <= 48)
      *(float4*)(z2p + ((size_t)((n * 32 + kc) * 49 + uv)) * 128 + eh0) = acc[uu];
  }
}

__global__ __launch_bounds__(128) void k3_merged(float* ws)
{
  __shared__ float Z2s[16][7][8];
  const int tid = threadIdx.x;
  const int bid = blockIdx.x;
  const int n = bid >> 7, rest = bid & 127;
  const int ec = rest >> 4, hq = rest & 15;
  const int c0 = ec * 16, h0 = hq * 2;
  const float* z2p = ws + WS_Z2P;
  const float* bf = ws + WS_BF;
  for (int idx = tid; idx < 784; idx += 128) {
    const int cl = idx & 15, uv = idx >> 4;
    float s = bf[c0 + cl];
    const float* p = z2p + (size_t)(n * 1568 + uv) * 128 + (c0 + cl);
    #pragma unroll 8
    for (int kc = 0; kc < 32; kc++) s += p[(size_t)kc * 6272];
    Z2s[cl][uv / 7][uv % 7] = s;
  }
  for (int idx = tid; idx < 112; idx += 128)
    Z2s[idx / 7][idx % 7][7] = 0.f;
  __syncthreads();

  const int e = tid >> 4, row = (tid >> 3) & 1, wq = tid & 7;
  const int w0 = wq * 4;
  const float* tP = ws + WS_TP;
  float acc[4] = {0.f, 0.f, 0.f, 0.f};
  #pragma unroll
  for (int h128 = 0; h128 < 2; h128++) {
    const int cl = 2 * e + h128;
    const float* tc = tP + (size_t)(128 * n + c0 + cl) * 1520;
    #pragma unroll
    for (int u = 0; u < 7; u++) {
      const float* trow = tc + (h0 + row + u) * 40 + w0;
      float tw[12];
      *(float4*)&tw[0] = *(const float4*)(trow);
      *(float4*)&tw[4] = *(const float4*)(trow + 4);
      *(float4*)&tw[8] = *(const float4*)(trow + 8);
      float z[8];
      *(float4*)&z[0] = *(const float4*)&Z2s[cl][u][0];
      *(float4*)&z[4] = *(const float4*)&Z2s[cl][u][4];
      #pragma unroll
      for (int px = 0; px < 4; px++)
        #pragma unroll
        for (int v = 0; v < 8; v++)
          acc[px] = fmaf(z[v], tw[px + v], acc[px]);
    }
  }
  float* mrg = ws + WS_MRG;
  *(float4*)(mrg + (size_t)(((n * 64 + ec * 8 + e) * 32) + h0 + row) * 32 + w0) =
      make_float4(acc[0], acc[1], acc[2], acc[3]);
}

__global__ __launch_bounds__(256) void k4_heads(
    const float* __restrict__ cb,
    const float* __restrict__ wcls, const float* __restrict__ bcls,
    const float* __restrict__ wbox, const float* __restrict__ bbox,
    float* ws, float* __restrict__ out)
{
  __shared__ float mrg_l[32][66];
  __shared__ float wcb_l[54][64];
  __shared__ float bias_l[54];
  __shared__ float logits[18][32];
  const int tid = threadIdx.x;
  const int n = blockIdx.x >> 5, h = blockIdx.x & 31;
  const float* mrg = ws + WS_MRG;
  for (int idx = tid; idx < 2048; idx += 256) {
    const int e = idx >> 5, w = idx & 31;
    mrg_l[w][e] = mrg[(size_t)(((n * 64 + e) * 32) + h) * 32 + w] + cb[e];
  }
  for (int idx = tid; idx < 3456; idx += 256) {
    const int ch = idx >> 6, e = idx & 63;
    wcb_l[ch][e] = (ch < 18) ? wcls[ch * 64 + e] : wbox[(ch - 18) * 64 + e];
  }
  if (tid < 54) bias_l[tid] = (tid < 18) ? bcls[tid] : bbox[tid - 18];
  __syncthreads();

  const int w = tid & 31, chg = tid >> 5;
  const int cnt = (chg < 6) ? 7 : 6;
  float acc[7] = {0.f, 0.f, 0.f, 0.f, 0.f, 0.f, 0.f};
  for (int e2 = 0; e2 < 32; e2++) {
    const float2 m2 = *(const float2*)&mrg_l[w][e2 * 2];
    #pragma unroll
    for (int i = 0; i < 7; i++) {
      if (i < cnt) {
        const int ch = chg + 8 * i;
        const float2 wv = *(const float2*)&wcb_l[ch][e2 * 2];
        acc[i] = fmaf(m2.x, wv.x, acc[i]);
        acc[i] = fmaf(m2.y, wv.y, acc[i]);
      }
    }
  }
  #pragma unroll
  for (int i = 0; i < 7; i++) {
    if (i < cnt) {
      const int ch = chg + 8 * i;
      const float v = acc[i] + bias_l[ch];
      if (ch < 18) logits[ch][w] = v;
      else out[36864 + n * 36864 + (ch - 18) * 1024 + h * 32 + w] = v;
    }
  }
  __syncthreads();
  for (int idx = tid; idx < 576; idx += 256) {
    const int ch = idx >> 5, w2 = idx & 31;
    const float a = logits[ch][w2];
    const float b = logits[(ch + 9) % 18][w2];
    const float m = fmaxf(a, b);
    const float ea = expf(a - m), eb = expf(b - m);
    out[n * 18432 + ch * 1024 + h * 32 + w2] = ea / (ea + eb);
  }
}

extern "C" void kernel_launch(void* const* d_in, const int* in_sizes, int n_in,
                              void* d_out, int out_size, void* d_ws, size_t ws_size,
                              hipStream_t stream) {
  (void)in_sizes; (void)n_in; (void)out_size; (void)ws_size;
  const float* target_feat   = (const float*)d_in[0];
  const float* template_feat = (const float*)d_in[1];
  const float* w_target      = (const float*)d_in[2];
  const float* b_target      = (const float*)d_in[3];
  const float* bn_gamma      = (const float*)d_in[4];
  const float* bn_beta       = (const float*)d_in[5];
  const float* bn_mean       = (const float*)d_in[6];
  const float* bn_var        = (const float*)d_in[7];
  const float* w_template    = (const float*)d_in[8];
  const float* b_template    = (const float*)d_in[9];
  const float* w_merge       = (const float*)d_in[10];
  const float* corr_bias     = (const float*)d_in[11];
  const float* w_cls         = (const float*)d_in[12];
  const float* b_cls         = (const float*)d_in[13];
  const float* w_box         = (const float*)d_in[14];
  const float* b_box         = (const float*)d_in[15];
  float* ws = (float*)d_ws;
  float* out = (float*)d_out;

  hipLaunchKernelGGL(k_fold, dim3(2304), dim3(256), 0, stream,
                     w_template, w_merge, ws);
  hipLaunchKernelGGL(k0_prep, dim3(2048), dim3(256), 0, stream,
                     target_feat, w_merge, b_template, ws);
  hipLaunchKernelGGL(k_conv, dim3(2048), dim3(256), 0, stream,
                     w_target, ws);
  hipLaunchKernelGGL(k_cred, dim3(256), dim3(256), 0, stream,
                     b_target, bn_gamma, bn_beta, bn_mean, bn_var, ws);
  hipLaunchKernelGGL(k2_z2, dim3(64), dim3(256), 0, stream,
                     template_feat, ws);
  hipLaunchKernelGGL(k3_merged, dim3(256), dim3(128), 0, stream, ws);
  hipLaunchKernelGGL(k4_heads, dim3(64), dim3(256), 0, stream,
                     corr_bias, w_cls, b_cls, w_box, b_box, ws, out);
}